// Round 10
// baseline (239.344 us; speedup 1.0000x reference)
//
#include <hip/hip_runtime.h>
#include <hip/hip_bf16.h>
#include <math.h>
#include <stdint.h>

#define N_TOK 8192
#define D_IN  1024
#define D_H   128
#define SPLIT 8

typedef __bf16 bf16;
typedef __attribute__((ext_vector_type(4))) __bf16 bf16x4;
typedef __attribute__((ext_vector_type(8))) __bf16 bf16x8;
typedef __attribute__((ext_vector_type(4))) float floatx4;

#define MFMA16(a, b, c) __builtin_amdgcn_mfma_f32_16x16x32_bf16((a), (b), (c), 0, 0, 0)

// sqrt(128) * log2(e): softmax in exp2 domain (combine uses exp2f to match).
#define QSCALE 16.322625246404958f

__device__ __forceinline__ uint32_t pack2(float a, float b) {
    union { bf16 h[2]; uint32_t u; } z;
    z.h[0] = (bf16)a; z.h[1] = (bf16)b; return z.u;
}

// V fragment order (A-frag of V^T == B-frag of V): [ntile][dt][lane][j]
__device__ __forceinline__ size_t vtf_idx(int n, int d) {
    return ((size_t)((n >> 6) * 8 + (d >> 4)) << 10)
         + (((n >> 3) & 7) << 7) + ((d & 15) << 3) + (n & 7);
}
// K fragment order (A-frag of K == B-frag of K^T): [ktile][kc][mt][lane][j]
__device__ __forceinline__ size_t khf_idx(int n, int d) {
    return ((size_t)(((n >> 6) * 4 + (d >> 5)) * 4 + ((n >> 4) & 3)) << 9)
         + (((d >> 3) & 3) << 7) + ((n & 15) << 3) + (d & 7);
}

#define X_OCT (N_TOK * D_IN / 8)
#define W_OCT (3 * D_H * D_IN / 8)

// ---------------------------------------------------------------------------
// Kernel 0: one-time fp32 -> split-bf16 conversion into MFMA fragment order.
// ---------------------------------------------------------------------------
__global__ __launch_bounds__(256)
void convert_kernel(const float* __restrict__ x,
                    const float* __restrict__ Wq,
                    const float* __restrict__ Wk,
                    const float* __restrict__ Wv,
                    bf16* __restrict__ xhf, bf16* __restrict__ xlf,
                    bf16* __restrict__ whf, bf16* __restrict__ wlf)
{
    const int gid = blockIdx.x * 256 + threadIdx.x;
    const float* src;
    bf16 *dh, *dl;
    size_t doff;
    if (gid < X_OCT) {
        int lane = gid & 63, fc = gid >> 6;
        int kc = fc & 31, mt = fc >> 5;
        int n  = mt * 16 + (lane & 15);
        int k0 = kc * 32 + ((lane >> 4) << 3);
        src = x + (size_t)n * D_IN + k0;
        dh = xhf; dl = xlf; doff = (size_t)gid << 3;
    } else {
        int w = gid - X_OCT;
        int y = w >> 14, r = w & 16383;
        int lane = r & 63, fc = r >> 6;
        int kc = fc & 31, ct = fc >> 5;
        int col = ct * 16 + (lane & 15);
        int k0  = kc * 32 + ((lane >> 4) << 3);
        const float* W = (y == 0) ? Wq : (y == 1) ? Wk : Wv;
        src = W + (size_t)col * D_IN + k0;
        dh = whf; dl = wlf; doff = (size_t)w << 3;
    }
    float4 a = *(const float4*)src;
    float4 b = *(const float4*)(src + 4);
    float vv[8] = { a.x, a.y, a.z, a.w, b.x, b.y, b.z, b.w };
    bf16x8 h, l;
    #pragma unroll
    for (int j = 0; j < 8; ++j) {
        bf16 hh = (bf16)vv[j];
        h[j] = hh;
        l[j] = (bf16)(vv[j] - (float)hh);
    }
    *(bf16x8*)(dh + doff) = h;
    *(bf16x8*)(dl + doff) = l;
}

// ---------------------------------------------------------------------------
// Kernel 1: QKV projection, FUSED over q/k/v, barrier-free, zero LDS.
// grid 256 x 512 threads (8 waves). Block = 32 rows x ALL 384 output cols:
// x frags read ONCE (not 3x as before); W read direct from global (1.5 MB
// total -> resident in every XCD's L2). Wave = 1 mtile x 6 col-tiles
// (ctg 0..23 spans y=q,k,v). No __syncthreads -> waves free-run and hide
// each other's load latency.
// ---------------------------------------------------------------------------
__global__ __launch_bounds__(512)
void qkv_kernel(const bf16* __restrict__ xhf, const bf16* __restrict__ xlf,
                const bf16* __restrict__ whf, const bf16* __restrict__ wlf,
                bf16* __restrict__ q_hi, bf16* __restrict__ q_lo,
                bf16* __restrict__ khf, bf16* __restrict__ klf,
                bf16* __restrict__ vtf)
{
    const int t    = threadIdx.x;
    const int lane = t & 63;
    const int wid  = t >> 6;            // 0..7
    const int lid  = lane & 15;
    const int quad = lane >> 4;
    const int mt   = blockIdx.x * 2 + (wid & 1);
    const int ctg0 = (wid >> 1) * 6;    // 0,6,12,18

    floatx4 acc[6];
    #pragma unroll
    for (int j = 0; j < 6; ++j)
        #pragma unroll
        for (int r = 0; r < 4; ++r) acc[j][r] = 0.f;

    #pragma unroll 4
    for (int kc = 0; kc < 32; ++kc) {
        const size_t xb = ((size_t)(mt * 32 + kc) << 9) + (lane << 3);
        bf16x8 ah = *(const bf16x8*)(xhf + xb);
        bf16x8 al = *(const bf16x8*)(xlf + xb);
        #pragma unroll
        for (int j = 0; j < 6; ++j) {
            const int ctg = ctg0 + j;
            const int y = ctg >> 3, ct = ctg & 7;
            const size_t wb = ((size_t)y << 17)
                            + ((size_t)(ct * 32 + kc) << 9) + (lane << 3);
            bf16x8 bh = *(const bf16x8*)(whf + wb);
            bf16x8 bl = *(const bf16x8*)(wlf + wb);
            acc[j] = MFMA16(ah, bh, acc[j]);
            acc[j] = MFMA16(al, bh, acc[j]);
            acc[j] = MFMA16(ah, bl, acc[j]);
        }
    }

    // epilogue: C-layout row = mt*16 + quad*4 + r, col = ct*16 + lid
    #pragma unroll
    for (int j = 0; j < 6; ++j) {
        const int ctg = ctg0 + j;
        const int y = ctg >> 3, ct = ctg & 7;
        #pragma unroll
        for (int r = 0; r < 4; ++r) {
            const int row = mt * 16 + quad * 4 + r;
            const int col = ct * 16 + lid;
            float a = acc[j][r];
            if (y == 0) {
                a *= QSCALE;
                bf16 h = (bf16)a;
                q_hi[(size_t)row * D_H + col] = h;
                q_lo[(size_t)row * D_H + col] = (bf16)(a - (float)h);
            } else if (y == 1) {
                bf16 h = (bf16)a;
                size_t idx = khf_idx(row, col);
                khf[idx] = h;
                klf[idx] = (bf16)(a - (float)h);
            } else {
                vtf[vtf_idx(row, col)] = (bf16)a;
            }
        }
    }
}

// ---------------------------------------------------------------------------
// Kernel 2: flash attention — BARRIER-FREE, ZERO LDS. Transposed form:
// S^T = K.Q^T, O^T = V^T.P^T with P^T built in-register via lane shuffles.
// K and V fragments read direct from global in fragment order (coalesced
// 1 KB/instruction, L2-served). No __syncthreads in the kernel -> the two
// waves per SIMD de-phase, so one wave's serial softmax chain overlaps the
// other's MFMA burst (R9's 30% phase-lock stall).
// XCD swizzle: sp = blockIdx.x & 7 pins each key-split's 1.25 MB working
// set (khf+klf+vtf slices) to one XCD's 4 MB L2.
// grid 512 = 2 blocks/CU; launch_bounds(256,2) (min-3 provably spills).
// ---------------------------------------------------------------------------
#define BQ   128
#define BKEY 64

__global__ __launch_bounds__(256, 2)
void flash_kernel(const bf16* __restrict__ qh, const bf16* __restrict__ ql,
                  const bf16* __restrict__ khf, const bf16* __restrict__ klf,
                  const bf16* __restrict__ vtf,
                  bf16*  __restrict__ opart,   // [SPLIT][N][D_H] unnormalized
                  float* __restrict__ mpart,   // [SPLIT][N] (exp2 domain)
                  float* __restrict__ lpart)   // [SPLIT][N]
{
    const int t     = threadIdx.x;
    const int lane  = t & 63;
    const int wid   = t >> 6;
    const int lid   = lane & 15;
    const int quad  = lane >> 4;
    const int sp    = blockIdx.x & 7;          // XCD-aligned split id
    const int q0    = (blockIdx.x >> 3) * BQ;
    const int strip = wid * 32;
    const int tile0 = sp * (N_TOK / BKEY / SPLIT);
    const int tile1 = tile0 + (N_TOK / BKEY / SPLIT);

    // Q as B-operand of Q^T (resident)
    bf16x8 b_hi[2][4], b_lo[2][4];
    #pragma unroll
    for (int ct = 0; ct < 2; ++ct) {
        const size_t rowb = (size_t)(q0 + strip + ct * 16 + lid) * D_H + quad * 8;
        #pragma unroll
        for (int kc = 0; kc < 4; ++kc) {
            b_hi[ct][kc] = *(const bf16x8*)(qh + rowb + kc * 32);
            b_lo[ct][kc] = *(const bf16x8*)(ql + rowb + kc * 32);
        }
    }

    bf16x8 vones;
    #pragma unroll
    for (int j = 0; j < 8; ++j) vones[j] = (bf16)1.0f;

    float m_run[2] = { -INFINITY, -INFINITY };
    floatx4 l_acc[2];
    #pragma unroll
    for (int ct = 0; ct < 2; ++ct)
        #pragma unroll
        for (int r = 0; r < 4; ++r) l_acc[ct][r] = 0.f;
    floatx4 o_acc[8][2];
    #pragma unroll
    for (int dt = 0; dt < 8; ++dt)
        #pragma unroll
        for (int ct = 0; ct < 2; ++ct)
            #pragma unroll
            for (int r = 0; r < 4; ++r) o_acc[dt][ct][r] = 0.f;

    for (int tt = tile0; tt < tile1; ++tt) {
        const bf16* kbh = khf + ((size_t)tt << 13);
        const bf16* kbl = klf + ((size_t)tt << 13);

        // ---- S^T = K . Q^T : split-bf16 3-pass, 96 MFMA, K direct global ----
        floatx4 s[4][2];
        #pragma unroll
        for (int mt = 0; mt < 4; ++mt)
            #pragma unroll
            for (int ct = 0; ct < 2; ++ct)
                #pragma unroll
                for (int r = 0; r < 4; ++r) s[mt][ct][r] = 0.f;

        #pragma unroll
        for (int kc = 0; kc < 4; ++kc) {
            bf16x8 ah[4], al[4];
            #pragma unroll
            for (int mt = 0; mt < 4; ++mt) {
                const int fo = ((kc * 4 + mt) << 9) + (lane << 3);
                ah[mt] = *(const bf16x8*)(kbh + fo);
                al[mt] = *(const bf16x8*)(kbl + fo);
            }
            #pragma unroll
            for (int mt = 0; mt < 4; ++mt)
                #pragma unroll
                for (int ct = 0; ct < 2; ++ct) {
                    s[mt][ct] = MFMA16(ah[mt], b_hi[ct][kc], s[mt][ct]);
                    s[mt][ct] = MFMA16(al[mt], b_hi[ct][kc], s[mt][ct]);
                    s[mt][ct] = MFMA16(ah[mt], b_lo[ct][kc], s[mt][ct]);
                }
        }

        // ---- softmax (exp2 domain): in-lane max over 16 keys + 2 shfl ----
        float alpha[2];
        uint32_t u0[4][2], u1[4][2];
        #pragma unroll
        for (int ct = 0; ct < 2; ++ct) {
            float mx = s[0][ct][0];
            #pragma unroll
            for (int mt = 0; mt < 4; ++mt)
                #pragma unroll
                for (int r = 0; r < 4; ++r)
                    mx = fmaxf(mx, s[mt][ct][r]);
            mx = fmaxf(mx, __shfl_xor(mx, 16, 64));
            mx = fmaxf(mx, __shfl_xor(mx, 32, 64));
            float mn = fmaxf(m_run[ct], mx);
            alpha[ct] = exp2f(m_run[ct] - mn);
            m_run[ct] = mn;
            #pragma unroll
            for (int mt = 0; mt < 4; ++mt) {
                float p0 = exp2f(s[mt][ct][0] - mn);
                float p1 = exp2f(s[mt][ct][1] - mn);
                float p2 = exp2f(s[mt][ct][2] - mn);
                float p3 = exp2f(s[mt][ct][3] - mn);
                u0[mt][ct] = pack2(p0, p1);
                u1[mt][ct] = pack2(p2, p3);
            }
        }

        // ---- build P^T B-frags in-register (lane permutation, R9-verified) ----
        bf16x8 pB[2][2];
        {
            const int lsrc = ((quad & 1) << 5) + lid;
            const bool himt = (quad & 2) != 0;
            #pragma unroll
            for (int kc2 = 0; kc2 < 2; ++kc2)
                #pragma unroll
                for (int ct = 0; ct < 2; ++ct) {
                    const int mA = kc2 * 2, mB = kc2 * 2 + 1;
                    uint32_t w0a = __shfl((int)u0[mA][ct], lsrc, 64);
                    uint32_t w0b = __shfl((int)u0[mB][ct], lsrc, 64);
                    uint32_t w1a = __shfl((int)u1[mA][ct], lsrc, 64);
                    uint32_t w1b = __shfl((int)u1[mB][ct], lsrc, 64);
                    uint32_t w2a = __shfl((int)u0[mA][ct], lsrc + 16, 64);
                    uint32_t w2b = __shfl((int)u0[mB][ct], lsrc + 16, 64);
                    uint32_t w3a = __shfl((int)u1[mA][ct], lsrc + 16, 64);
                    uint32_t w3b = __shfl((int)u1[mB][ct], lsrc + 16, 64);
                    union { uint32_t w[4]; bf16x8 v; } z;
                    z.w[0] = himt ? w0b : w0a;
                    z.w[1] = himt ? w1b : w1a;
                    z.w[2] = himt ? w2b : w2a;
                    z.w[3] = himt ? w3b : w3a;
                    pB[kc2][ct] = z.v;
                }
        }

        // ---- V group 0 loads (overlap the rescale VALU below) ----
        const bf16* vb = vtf + ((size_t)tt << 13) + (lane << 3);
        bf16x8 vf0[8];
        #pragma unroll
        for (int dt = 0; dt < 8; ++dt)
            vf0[dt] = *(const bf16x8*)(vb + ((size_t)dt << 10));

        // ---- rescale (skip when all alphas are 1) ----
        if (__any(alpha[0] != 1.0f || alpha[1] != 1.0f)) {
            #pragma unroll
            for (int ct = 0; ct < 2; ++ct) {
                #pragma unroll
                for (int r = 0; r < 4; ++r) l_acc[ct][r] *= alpha[ct];
                #pragma unroll
                for (int dt = 0; dt < 8; ++dt)
                    #pragma unroll
                    for (int r = 0; r < 4; ++r)
                        o_acc[dt][ct][r] *= alpha[ct];
            }
        }

        // ---- O^T += V^T P^T ; l += ones.P^T  (two kc2 halves) ----
        #pragma unroll
        for (int ct = 0; ct < 2; ++ct)
            l_acc[ct] = MFMA16(vones, pB[0][ct], l_acc[ct]);
        #pragma unroll
        for (int dt = 0; dt < 8; ++dt)
            #pragma unroll
            for (int ct = 0; ct < 2; ++ct)
                o_acc[dt][ct] = MFMA16(vf0[dt], pB[0][ct], o_acc[dt][ct]);

        bf16x8 vf1[8];
        #pragma unroll
        for (int dt = 0; dt < 8; ++dt)
            vf1[dt] = *(const bf16x8*)(vb + ((size_t)dt << 10) + 512);
        #pragma unroll
        for (int ct = 0; ct < 2; ++ct)
            l_acc[ct] = MFMA16(vones, pB[1][ct], l_acc[ct]);
        #pragma unroll
        for (int dt = 0; dt < 8; ++dt)
            #pragma unroll
            for (int ct = 0; ct < 2; ++ct)
                o_acc[dt][ct] = MFMA16(vf1[dt], pB[1][ct], o_acc[dt][ct]);
    }

    // ---- epilogue: O^T regs -> opart[qrow][d] (packed u32 stores) ----
    uint32_t* opw = (uint32_t*)(opart + (size_t)sp * N_TOK * D_H);
    #pragma unroll
    for (int dt = 0; dt < 8; ++dt)
        #pragma unroll
        for (int ct = 0; ct < 2; ++ct) {
            int qrow  = q0 + strip + ct * 16 + lid;
            int dbase = dt * 16 + quad * 4;
            opw[(qrow * D_H + dbase) >> 1]     = pack2(o_acc[dt][ct][0], o_acc[dt][ct][1]);
            opw[(qrow * D_H + dbase + 2) >> 1] = pack2(o_acc[dt][ct][2], o_acc[dt][ct][3]);
        }
    if (quad == 0) {
        #pragma unroll
        for (int ct = 0; ct < 2; ++ct) {
            int row = q0 + strip + ct * 16 + lid;
            mpart[(size_t)sp * N_TOK + row] = m_run[ct];
            lpart[(size_t)sp * N_TOK + row] = l_acc[ct][0];
        }
    }
}

// ---------------------------------------------------------------------------
// Kernel 3: merge the SPLIT partials (exp2 domain).
// ---------------------------------------------------------------------------
__global__ __launch_bounds__(256)
void combine_kernel(const bf16* __restrict__ opart,
                    const float* __restrict__ mpart,
                    const float* __restrict__ lpart,
                    float* __restrict__ out)
{
    const int t   = threadIdx.x;
    const int row = blockIdx.x * 16 + (t >> 4);
    const int c0  = (t & 15) * 8;

    float ms[SPLIT], ls[SPLIT];
    float mstar = -INFINITY;
    #pragma unroll
    for (int s = 0; s < SPLIT; ++s) {
        ms[s] = mpart[(size_t)s * N_TOK + row];
        ls[s] = lpart[(size_t)s * N_TOK + row];
        mstar = fmaxf(mstar, ms[s]);
    }
    float acc[8] = {};
    float L = 0.f;
    #pragma unroll
    for (int s = 0; s < SPLIT; ++s) {
        float w = exp2f(ms[s] - mstar);
        L += w * ls[s];
        bf16x8 o = *(const bf16x8*)&opart[((size_t)s * N_TOK + row) * D_H + c0];
        #pragma unroll
        for (int j = 0; j < 8; ++j)
            acc[j] += w * (float)o[j];
    }
    float inv = 1.f / L;
    float* dst = &out[(size_t)row * D_H + c0];
    *(float4*)(dst + 0) = make_float4(acc[0] * inv, acc[1] * inv,
                                      acc[2] * inv, acc[3] * inv);
    *(float4*)(dst + 4) = make_float4(acc[4] * inv, acc[5] * inv,
                                      acc[6] * inv, acc[7] * inv);
}

// ---------------------------------------------------------------------------
extern "C" void kernel_launch(void* const* d_in, const int* in_sizes, int n_in,
                              void* d_out, int out_size, void* d_ws, size_t ws_size,
                              hipStream_t stream) {
    const float* x  = (const float*)d_in[0];
    const float* Wq = (const float*)d_in[1];
    const float* Wk = (const float*)d_in[2];
    const float* Wv = (const float*)d_in[3];
    float* out = (float*)d_out;

    bf16* wsb = (bf16*)d_ws;
    const size_t SZ = (size_t)N_TOK * D_H;
    bf16* xhf = wsb;
    bf16* xlf = xhf + (size_t)X_OCT * 8;
    bf16* whf = xlf + (size_t)X_OCT * 8;
    bf16* wlf = whf + (size_t)W_OCT * 8;
    bf16* qh  = wlf + (size_t)W_OCT * 8;
    bf16* ql  = qh + SZ;
    bf16* khf = ql + SZ;
    bf16* klf = khf + SZ;
    bf16* vtf = klf + SZ;
    bf16* opart = vtf + SZ;
    float* mpart = (float*)(opart + (size_t)SPLIT * SZ);
    float* lpart = mpart + (size_t)SPLIT * N_TOK;

    convert_kernel<<<dim3((X_OCT + W_OCT) / 256), 256, 0, stream>>>(
        x, Wq, Wk, Wv, xhf, xlf, whf, wlf);
    qkv_kernel<<<dim3(N_TOK / 32), 512, 0, stream>>>(
        xhf, xlf, whf, wlf, qh, ql, khf, klf, vtf);
    flash_kernel<<<dim3((N_TOK / BQ) * SPLIT), 256, 0, stream>>>(
        qh, ql, khf, klf, vtf, opart, mpart, lpart);
    combine_kernel<<<dim3(N_TOK / 16), 256, 0, stream>>>(opart, mpart, lpart, out);
}

// Round 11
// 223.834 us; speedup vs baseline: 1.0693x; 1.0693x over previous
//
#include <hip/hip_runtime.h>
#include <hip/hip_bf16.h>
#include <math.h>
#include <stdint.h>

#define N_TOK 8192
#define D_IN  1024
#define D_H   128
#define SPLIT 8

typedef __bf16 bf16;
typedef __attribute__((ext_vector_type(4))) __bf16 bf16x4;
typedef __attribute__((ext_vector_type(8))) __bf16 bf16x8;
typedef __attribute__((ext_vector_type(4))) float floatx4;

#define MFMA16(a, b, c) __builtin_amdgcn_mfma_f32_16x16x32_bf16((a), (b), (c), 0, 0, 0)

// sqrt(128) * log2(e): softmax in exp2 domain (combine uses exp2f to match).
#define QSCALE 16.322625246404958f

__device__ __forceinline__ uint32_t pack2(float a, float b) {
    union { bf16 h[2]; uint32_t u; } z;
    z.h[0] = (bf16)a; z.h[1] = (bf16)b; return z.u;
}

// V fragment order (A-frag of V^T == B-frag of V): [ntile][dt][lane][j]
__device__ __forceinline__ size_t vtf_idx(int n, int d) {
    return ((size_t)((n >> 6) * 8 + (d >> 4)) << 10)
         + (((n >> 3) & 7) << 7) + ((d & 15) << 3) + (n & 7);
}
// K fragment order (A-frag of K == B-frag of K^T): [ktile][kc][mt][lane][j]
__device__ __forceinline__ size_t khf_idx(int n, int d) {
    return ((size_t)(((n >> 6) * 4 + (d >> 5)) * 4 + ((n >> 4) & 3)) << 9)
         + (((d >> 3) & 3) << 7) + ((n & 15) << 3) + (d & 7);
}

#define X_OCT (N_TOK * D_IN / 8)
#define W_OCT (3 * D_H * D_IN / 8)

// ---------------------------------------------------------------------------
// Kernel 0: one-time fp32 -> split-bf16 conversion into MFMA fragment order.
// ---------------------------------------------------------------------------
__global__ __launch_bounds__(256)
void convert_kernel(const float* __restrict__ x,
                    const float* __restrict__ Wq,
                    const float* __restrict__ Wk,
                    const float* __restrict__ Wv,
                    bf16* __restrict__ xhf, bf16* __restrict__ xlf,
                    bf16* __restrict__ whf, bf16* __restrict__ wlf)
{
    const int gid = blockIdx.x * 256 + threadIdx.x;
    const float* src;
    bf16 *dh, *dl;
    size_t doff;
    if (gid < X_OCT) {
        int lane = gid & 63, fc = gid >> 6;
        int kc = fc & 31, mt = fc >> 5;
        int n  = mt * 16 + (lane & 15);
        int k0 = kc * 32 + ((lane >> 4) << 3);
        src = x + (size_t)n * D_IN + k0;
        dh = xhf; dl = xlf; doff = (size_t)gid << 3;
    } else {
        int w = gid - X_OCT;
        int y = w >> 14, r = w & 16383;
        int lane = r & 63, fc = r >> 6;
        int kc = fc & 31, ct = fc >> 5;
        int col = ct * 16 + (lane & 15);
        int k0  = kc * 32 + ((lane >> 4) << 3);
        const float* W = (y == 0) ? Wq : (y == 1) ? Wk : Wv;
        src = W + (size_t)col * D_IN + k0;
        dh = whf; dl = wlf; doff = (size_t)w << 3;
    }
    float4 a = *(const float4*)src;
    float4 b = *(const float4*)(src + 4);
    float vv[8] = { a.x, a.y, a.z, a.w, b.x, b.y, b.z, b.w };
    bf16x8 h, l;
    #pragma unroll
    for (int j = 0; j < 8; ++j) {
        bf16 hh = (bf16)vv[j];
        h[j] = hh;
        l[j] = (bf16)(vv[j] - (float)hh);
    }
    *(bf16x8*)(dh + doff) = h;
    *(bf16x8*)(dl + doff) = l;
}

// ---------------------------------------------------------------------------
// Kernel 1: QKV projection, split-bf16 3-pass MFMA, W staged per-kc in LDS.
// BM=32, grid (256, 3) = 768 blocks = EXACTLY 3 blocks/CU (R9's 384-block
// grid left half the CUs with one block). Block = 32 rows x 128 cols,
// 4 waves 2x2 (wave: 1 mtile x 4 ctiles). Per kc: 16 KB W chunk staged by
// async global_load_lds (dbuf 32 KB); x frag prefetched one kc ahead from
// global. 12 MFMA/wave/kc; MFMA-bound floor ~8 us at 3 waves/SIMD.
// ---------------------------------------------------------------------------
__global__ __launch_bounds__(256, 3)
void qkv_kernel(const bf16* __restrict__ xhf, const bf16* __restrict__ xlf,
                const bf16* __restrict__ whf, const bf16* __restrict__ wlf,
                bf16* __restrict__ q_hi, bf16* __restrict__ q_lo,
                bf16* __restrict__ khf, bf16* __restrict__ klf,
                bf16* __restrict__ vtf)
{
    __shared__ bf16 w_s[2][8192];   // [buf][(hl*8+ct)*512 + lane*8 + j]

    const int t    = threadIdx.x;
    const int lane = t & 63;
    const int wid  = t >> 6;         // 0..3
    const int wr   = wid >> 1;       // mtile half
    const int wc   = wid & 1;        // col half (4 ct each)
    const int lid  = lane & 15;
    const int quad = lane >> 4;
    const int mt   = blockIdx.x * 2 + wr;
    const int y    = blockIdx.y;
    const bf16* wh = whf + ((size_t)y << 17);
    const bf16* wl = wlf + ((size_t)y << 17);

    // wave stages 4 of the 16 frag-blocks (hl*8+ct) of the kc chunk
    auto stage = [&](int kc, int buf) {
        #pragma unroll
        for (int i = 0; i < 4; ++i) {
            int b  = wid * 4 + i;
            int hl = b >> 3, ct = b & 7;
            const bf16* src = (hl ? wl : wh)
                            + ((size_t)(ct * 32 + kc) << 9) + (lane << 3);
            bf16* dst = &w_s[buf][(b << 9) + (lane << 3)];
            __builtin_amdgcn_global_load_lds(
                (const __attribute__((address_space(1))) void*)src,
                (__attribute__((address_space(3))) void*)dst, 16, 0, 0);
        }
    };

    floatx4 acc[4];
    #pragma unroll
    for (int ct = 0; ct < 4; ++ct)
        #pragma unroll
        for (int r = 0; r < 4; ++r) acc[ct][r] = 0.f;

    stage(0, 0);
    bf16x8 ah, al;
    {
        const size_t xb = ((size_t)(mt * 32) << 9) + (lane << 3);
        ah = *(const bf16x8*)(xhf + xb);
        al = *(const bf16x8*)(xlf + xb);
    }

    #pragma unroll 2
    for (int kc = 0; kc < 32; ++kc) {
        const int cb = kc & 1;
        __syncthreads();                 // W(kc) staged+drained; buf cb^1 free
        if (kc < 31) stage(kc + 1, cb ^ 1);
        bf16x8 ahn, aln;
        if (kc < 31) {
            const size_t xb = ((size_t)(mt * 32 + kc + 1) << 9) + (lane << 3);
            ahn = *(const bf16x8*)(xhf + xb);
            aln = *(const bf16x8*)(xlf + xb);
        }
        #pragma unroll
        for (int ct = 0; ct < 4; ++ct) {
            bf16x8 bh = *(const bf16x8*)&w_s[cb][((wc * 4 + ct) << 9) + (lane << 3)];
            bf16x8 bl = *(const bf16x8*)&w_s[cb][((8 + wc * 4 + ct) << 9) + (lane << 3)];
            acc[ct] = MFMA16(ah, bh, acc[ct]);
            acc[ct] = MFMA16(al, bh, acc[ct]);
            acc[ct] = MFMA16(ah, bl, acc[ct]);
        }
        ah = ahn; al = aln;
    }

    // epilogue: C-layout row = mt*16 + quad*4 + r, col = wc*64 + ct*16 + lid
    #pragma unroll
    for (int ct = 0; ct < 4; ++ct)
        #pragma unroll
        for (int r = 0; r < 4; ++r) {
            const int row = mt * 16 + quad * 4 + r;
            const int col = wc * 64 + ct * 16 + lid;
            float a = acc[ct][r];
            if (y == 0) {
                a *= QSCALE;
                bf16 h = (bf16)a;
                q_hi[(size_t)row * D_H + col] = h;
                q_lo[(size_t)row * D_H + col] = (bf16)(a - (float)h);
            } else if (y == 1) {
                bf16 h = (bf16)a;
                size_t idx = khf_idx(row, col);
                khf[idx] = h;
                klf[idx] = (bf16)(a - (float)h);
            } else {
                vtf[vtf_idx(row, col)] = (bf16)a;
            }
        }
}

// ---------------------------------------------------------------------------
// Kernel 2: flash attention, SOFTWARE-PIPELINED softmax. R9 structure
// (transposed form, LDS K dbuf shared by the block, 1 barrier/tile, P^T
// built in-register) but the loop computes S(t+1) BEFORE softmax(t): the
// 96 S-MFMAs and the serial softmax VALU chain are independent, so the
// SIMD interleaves them instead of exposing the softmax at the barrier
// (R9's ~30% stall). V direct from global in fragment order (block-shared
// data stays in LDS; V frags are wave-private usage anyway).
// grid 512 1D, sp = blockIdx.x & 7 (XCD-aligned key split).
// launch_bounds(256,2): min-3 provably spills (R4/R5/R7).
// ---------------------------------------------------------------------------
#define BQ   128
#define BKEY 64

__global__ __launch_bounds__(256, 2)
void flash_kernel(const bf16* __restrict__ qh, const bf16* __restrict__ ql,
                  const bf16* __restrict__ khf, const bf16* __restrict__ klf,
                  const bf16* __restrict__ vtf,
                  bf16*  __restrict__ opart,   // [SPLIT][N][D_H] unnormalized
                  float* __restrict__ mpart,   // [SPLIT][N] (exp2 domain)
                  float* __restrict__ lpart)   // [SPLIT][N]
{
    __shared__ bf16 k_s[2][16384];   // [buf][ kh: 0..8191 | kl: 8192..16383 ]

    const int t     = threadIdx.x;
    const int lane  = t & 63;
    const int wid   = t >> 6;
    const int lid   = lane & 15;
    const int quad  = lane >> 4;
    const int sp    = blockIdx.x & 7;
    const int q0    = (blockIdx.x >> 3) * BQ;
    const int strip = wid * 32;
    const int tile0 = sp * (N_TOK / BKEY / SPLIT);
    const int tile1 = tile0 + (N_TOK / BKEY / SPLIT);

    // Q as B-operand of Q^T (resident)
    bf16x8 b_hi[2][4], b_lo[2][4];
    #pragma unroll
    for (int ct = 0; ct < 2; ++ct) {
        const size_t rowb = (size_t)(q0 + strip + ct * 16 + lid) * D_H + quad * 8;
        #pragma unroll
        for (int kc = 0; kc < 4; ++kc) {
            b_hi[ct][kc] = *(const bf16x8*)(qh + rowb + kc * 32);
            b_lo[ct][kc] = *(const bf16x8*)(ql + rowb + kc * 32);
        }
    }

    bf16x8 vones;
    #pragma unroll
    for (int j = 0; j < 8; ++j) vones[j] = (bf16)1.0f;

    float m_run[2] = { -INFINITY, -INFINITY };
    floatx4 l_acc[2];
    #pragma unroll
    for (int ct = 0; ct < 2; ++ct)
        #pragma unroll
        for (int r = 0; r < 4; ++r) l_acc[ct][r] = 0.f;
    floatx4 o_acc[8][2];
    #pragma unroll
    for (int dt = 0; dt < 8; ++dt)
        #pragma unroll
        for (int ct = 0; ct < 2; ++ct)
            #pragma unroll
            for (int r = 0; r < 4; ++r) o_acc[dt][ct][r] = 0.f;

    auto stage = [&](int tile, int buf) {
        const bf16* gh = khf + ((size_t)tile << 13) + (wid << 11) + (lane << 3);
        const bf16* gl = klf + ((size_t)tile << 13) + (wid << 11) + (lane << 3);
        bf16* lh = &k_s[buf][wid << 11];
        bf16* ll = lh + 8192;
        #pragma unroll
        for (int i = 0; i < 4; ++i) {
            __builtin_amdgcn_global_load_lds(
                (const __attribute__((address_space(1))) void*)(gh + i * 512),
                (__attribute__((address_space(3))) void*)(lh + i * 512), 16, 0, 0);
            __builtin_amdgcn_global_load_lds(
                (const __attribute__((address_space(1))) void*)(gl + i * 512),
                (__attribute__((address_space(3))) void*)(ll + i * 512), 16, 0, 0);
        }
    };

    auto compute_S = [&](int cb, floatx4 (&s)[4][2]) {
        const bf16* khp = &k_s[cb][0];
        const bf16* klp = &k_s[cb][8192];
        #pragma unroll
        for (int mt = 0; mt < 4; ++mt)
            #pragma unroll
            for (int ct = 0; ct < 2; ++ct)
                #pragma unroll
                for (int r = 0; r < 4; ++r) s[mt][ct][r] = 0.f;
        #pragma unroll
        for (int kc = 0; kc < 4; ++kc)
            #pragma unroll
            for (int mt = 0; mt < 4; ++mt) {
                const int fo = ((kc * 4 + mt) << 9) + (lane << 3);
                bf16x8 ah = *(const bf16x8*)&khp[fo];
                bf16x8 al = *(const bf16x8*)&klp[fo];
                #pragma unroll
                for (int ct = 0; ct < 2; ++ct) {
                    s[mt][ct] = MFMA16(ah, b_hi[ct][kc], s[mt][ct]);
                    s[mt][ct] = MFMA16(al, b_hi[ct][kc], s[mt][ct]);
                    s[mt][ct] = MFMA16(ah, b_lo[ct][kc], s[mt][ct]);
                }
            }
    };

    // ---- prologue: K(t0) staged+consumed into S_prev; K(t0+1) in flight ----
    stage(tile0, 0);
    __syncthreads();
    if (tile0 + 1 < tile1) stage(tile0 + 1, 1);
    floatx4 sprev[4][2];
    compute_S(0, sprev);

    for (int tt = tile0; tt < tile1; ++tt) {
        const bool more = (tt + 1 < tile1);
        floatx4 snext[4][2];
        if (more) {
            __syncthreads();      // K(tt+1) staged by all waves + drained;
                                  // buf of K(tt) free (S(tt) done pre-barrier)
            if (tt + 2 < tile1) stage(tt + 2, (tt - tile0) & 1);
            compute_S((tt + 1 - tile0) & 1, snext);   // MFMA stream,
                                  // interleaves with softmax VALU below
        }

        // ---- V group 0 prefetch ----
        const bf16* vb = vtf + ((size_t)tt << 13) + (lane << 3);
        bf16x8 vf0[8];
        #pragma unroll
        for (int dt = 0; dt < 8; ++dt)
            vf0[dt] = *(const bf16x8*)(vb + ((size_t)dt << 10));

        // ---- softmax(tt) on sprev (exp2 domain) ----
        float alpha[2];
        uint32_t u0[4][2], u1[4][2];
        #pragma unroll
        for (int ct = 0; ct < 2; ++ct) {
            float mx = sprev[0][ct][0];
            #pragma unroll
            for (int mt = 0; mt < 4; ++mt)
                #pragma unroll
                for (int r = 0; r < 4; ++r)
                    mx = fmaxf(mx, sprev[mt][ct][r]);
            mx = fmaxf(mx, __shfl_xor(mx, 16, 64));
            mx = fmaxf(mx, __shfl_xor(mx, 32, 64));
            float mn = fmaxf(m_run[ct], mx);
            alpha[ct] = exp2f(m_run[ct] - mn);
            m_run[ct] = mn;
            #pragma unroll
            for (int mt = 0; mt < 4; ++mt) {
                float p0 = exp2f(sprev[mt][ct][0] - mn);
                float p1 = exp2f(sprev[mt][ct][1] - mn);
                float p2 = exp2f(sprev[mt][ct][2] - mn);
                float p3 = exp2f(sprev[mt][ct][3] - mn);
                u0[mt][ct] = pack2(p0, p1);
                u1[mt][ct] = pack2(p2, p3);
            }
        }

        // ---- build P^T B-frags in-register (lane permutation, R9-verified) ----
        bf16x8 pB[2][2];
        {
            const int lsrc = ((quad & 1) << 5) + lid;
            const bool himt = (quad & 2) != 0;
            #pragma unroll
            for (int kc2 = 0; kc2 < 2; ++kc2)
                #pragma unroll
                for (int ct = 0; ct < 2; ++ct) {
                    const int mA = kc2 * 2, mB = kc2 * 2 + 1;
                    uint32_t w0a = __shfl((int)u0[mA][ct], lsrc, 64);
                    uint32_t w0b = __shfl((int)u0[mB][ct], lsrc, 64);
                    uint32_t w1a = __shfl((int)u1[mA][ct], lsrc, 64);
                    uint32_t w1b = __shfl((int)u1[mB][ct], lsrc, 64);
                    uint32_t w2a = __shfl((int)u0[mA][ct], lsrc + 16, 64);
                    uint32_t w2b = __shfl((int)u0[mB][ct], lsrc + 16, 64);
                    uint32_t w3a = __shfl((int)u1[mA][ct], lsrc + 16, 64);
                    uint32_t w3b = __shfl((int)u1[mB][ct], lsrc + 16, 64);
                    union { uint32_t w[4]; bf16x8 v; } z;
                    z.w[0] = himt ? w0b : w0a;
                    z.w[1] = himt ? w1b : w1a;
                    z.w[2] = himt ? w2b : w2a;
                    z.w[3] = himt ? w3b : w3a;
                    pB[kc2][ct] = z.v;
                }
        }

        // ---- rescale (skip when all alphas are 1) ----
        if (__any(alpha[0] != 1.0f || alpha[1] != 1.0f)) {
            #pragma unroll
            for (int ct = 0; ct < 2; ++ct) {
                #pragma unroll
                for (int r = 0; r < 4; ++r) l_acc[ct][r] *= alpha[ct];
                #pragma unroll
                for (int dt = 0; dt < 8; ++dt)
                    #pragma unroll
                    for (int r = 0; r < 4; ++r)
                        o_acc[dt][ct][r] *= alpha[ct];
            }
        }

        // ---- O^T += V^T P^T ; l += ones.P^T  (two kc2 halves) ----
        #pragma unroll
        for (int ct = 0; ct < 2; ++ct)
            l_acc[ct] = MFMA16(vones, pB[0][ct], l_acc[ct]);
        #pragma unroll
        for (int dt = 0; dt < 8; ++dt)
            #pragma unroll
            for (int ct = 0; ct < 2; ++ct)
                o_acc[dt][ct] = MFMA16(vf0[dt], pB[0][ct], o_acc[dt][ct]);

        bf16x8 vf1[8];
        #pragma unroll
        for (int dt = 0; dt < 8; ++dt)
            vf1[dt] = *(const bf16x8*)(vb + ((size_t)dt << 10) + 512);
        #pragma unroll
        for (int ct = 0; ct < 2; ++ct)
            l_acc[ct] = MFMA16(vones, pB[1][ct], l_acc[ct]);
        #pragma unroll
        for (int dt = 0; dt < 8; ++dt)
            #pragma unroll
            for (int ct = 0; ct < 2; ++ct)
                o_acc[dt][ct] = MFMA16(vf1[dt], pB[1][ct], o_acc[dt][ct]);

        if (more) {
            #pragma unroll
            for (int mt = 0; mt < 4; ++mt)
                #pragma unroll
                for (int ct = 0; ct < 2; ++ct)
                    sprev[mt][ct] = snext[mt][ct];
        }
    }

    // ---- epilogue: O^T regs -> opart[qrow][d] (packed u32 stores) ----
    uint32_t* opw = (uint32_t*)(opart + (size_t)sp * N_TOK * D_H);
    #pragma unroll
    for (int dt = 0; dt < 8; ++dt)
        #pragma unroll
        for (int ct = 0; ct < 2; ++ct) {
            int qrow  = q0 + strip + ct * 16 + lid;
            int dbase = dt * 16 + quad * 4;
            opw[(qrow * D_H + dbase) >> 1]     = pack2(o_acc[dt][ct][0], o_acc[dt][ct][1]);
            opw[(qrow * D_H + dbase + 2) >> 1] = pack2(o_acc[dt][ct][2], o_acc[dt][ct][3]);
        }
    if (quad == 0) {
        #pragma unroll
        for (int ct = 0; ct < 2; ++ct) {
            int row = q0 + strip + ct * 16 + lid;
            mpart[(size_t)sp * N_TOK + row] = m_run[ct];
            lpart[(size_t)sp * N_TOK + row] = l_acc[ct][0];
        }
    }
}

// ---------------------------------------------------------------------------
// Kernel 3: merge the SPLIT partials (exp2 domain).
// ---------------------------------------------------------------------------
__global__ __launch_bounds__(256)
void combine_kernel(const bf16* __restrict__ opart,
                    const float* __restrict__ mpart,
                    const float* __restrict__ lpart,
                    float* __restrict__ out)
{
    const int t   = threadIdx.x;
    const int row = blockIdx.x * 16 + (t >> 4);
    const int c0  = (t & 15) * 8;

    float ms[SPLIT], ls[SPLIT];
    float mstar = -INFINITY;
    #pragma unroll
    for (int s = 0; s < SPLIT; ++s) {
        ms[s] = mpart[(size_t)s * N_TOK + row];
        ls[s] = lpart[(size_t)s * N_TOK + row];
        mstar = fmaxf(mstar, ms[s]);
    }
    float acc[8] = {};
    float L = 0.f;
    #pragma unroll
    for (int s = 0; s < SPLIT; ++s) {
        float w = exp2f(ms[s] - mstar);
        L += w * ls[s];
        bf16x8 o = *(const bf16x8*)&opart[((size_t)s * N_TOK + row) * D_H + c0];
        #pragma unroll
        for (int j = 0; j < 8; ++j)
            acc[j] += w * (float)o[j];
    }
    float inv = 1.f / L;
    float* dst = &out[(size_t)row * D_H + c0];
    *(float4*)(dst + 0) = make_float4(acc[0] * inv, acc[1] * inv,
                                      acc[2] * inv, acc[3] * inv);
    *(float4*)(dst + 4) = make_float4(acc[4] * inv, acc[5] * inv,
                                      acc[6] * inv, acc[7] * inv);
}

// ---------------------------------------------------------------------------
extern "C" void kernel_launch(void* const* d_in, const int* in_sizes, int n_in,
                              void* d_out, int out_size, void* d_ws, size_t ws_size,
                              hipStream_t stream) {
    const float* x  = (const float*)d_in[0];
    const float* Wq = (const float*)d_in[1];
    const float* Wk = (const float*)d_in[2];
    const float* Wv = (const float*)d_in[3];
    float* out = (float*)d_out;

    bf16* wsb = (bf16*)d_ws;
    const size_t SZ = (size_t)N_TOK * D_H;
    bf16* xhf = wsb;
    bf16* xlf = xhf + (size_t)X_OCT * 8;
    bf16* whf = xlf + (size_t)X_OCT * 8;
    bf16* wlf = whf + (size_t)W_OCT * 8;
    bf16* qh  = wlf + (size_t)W_OCT * 8;
    bf16* ql  = qh + SZ;
    bf16* khf = ql + SZ;
    bf16* klf = khf + SZ;
    bf16* vtf = klf + SZ;
    bf16* opart = vtf + SZ;
    float* mpart = (float*)(opart + (size_t)SPLIT * SZ);
    float* lpart = mpart + (size_t)SPLIT * N_TOK;

    convert_kernel<<<dim3((X_OCT + W_OCT) / 256), 256, 0, stream>>>(
        x, Wq, Wk, Wv, xhf, xlf, whf, wlf);
    qkv_kernel<<<dim3(N_TOK / 32, 3), 256, 0, stream>>>(
        xhf, xlf, whf, wlf, qh, ql, khf, klf, vtf);
    flash_kernel<<<dim3((N_TOK / BQ) * SPLIT), 256, 0, stream>>>(
        qh, ql, khf, klf, vtf, opart, mpart, lpart);
    combine_kernel<<<dim3(N_TOK / 16), 256, 0, stream>>>(opart, mpart, lpart, out);
}